// Round 4
// baseline (274.530 us; speedup 1.0000x reference)
//
#include <hip/hip_runtime.h>

// Fused Conv3d(3->16,k3,valid) + bias + /2 + MaxPool3d(2) + GlobalAvgPool + bias + channel-sum
// N=32, Cin=3, D=32,H=64,W=64 -> conv (30,62,62) -> pool (15,31,31) -> out (32)
//
// out[n] = (1/(2*14415)) * sum_{c,windows} max_window(conv_c) + sum_c( conv_bias_c/2 + bias_c )
//
// Spill-free layout: the 2x2x2 maxpool window is computed as two sequential
// conv-d slices (dd=0,1); each pass needs only acc[8][4] (2x2 hw window for
// 8 channels) + running per-channel max pm[8]. Rows of the 4x4 input patch
// are loaded on the fly (2x float2), so the live set stays ~56 VGPRs.

__global__ __launch_bounds__(256, 4) void conv_pool_kernel(
    const float* __restrict__ x, const float* __restrict__ wgt,
    float* __restrict__ ws)
{
  __shared__ float wsum[4];

  const int tid  = threadIdx.x;
  const int bx   = blockIdx.x;           // 0..7: tile = bx&3, channel-group g = bx>>2
  const int tile = bx & 3;
  const int g    = bx >> 2;              // channels g*8 .. g*8+7
  const int pht  = tile >> 1, pwt = tile & 1;
  const int pd   = blockIdx.y;           // 0..14
  const int n    = blockIdx.z;           // 0..31

  const int ty = tid >> 4, tx = tid & 15;
  const int ph = pht*16 + ty, pw = pwt*16 + tx;    // pooled coords, valid < 31
  const bool valid = (ph < 31) && (pw < 31);
  const int phc = (ph < 31) ? ph : 30;             // clamp: duplicate window, zeroed later
  const int pwc = (pw < 31) ? pw : 30;

  const float* xn = x + (size_t)n*(3*32*64*64) + (size_t)(2*pd)*(64*64);
  const int rowoff = (2*phc)*64 + 2*pwc;           // element offset within a d-slice

  float pm[8];
  #pragma unroll
  for (int c = 0; c < 8; ++c) pm[c] = -3.4e38f;

  #pragma unroll 1
  for (int dd = 0; dd < 2; ++dd) {                 // conv-d slice of the pool window
    float acc[8][4];
    #pragma unroll
    for (int c = 0; c < 8; ++c)
      #pragma unroll
      for (int i = 0; i < 4; ++i) acc[c][i] = 0.f;

    #pragma unroll 1
    for (int ci = 0; ci < 3; ++ci) {
      const float* xci = xn + (size_t)ci*(32*64*64) + rowoff;
      const float* wci = wgt + (size_t)(g*24 + ci)*27;   // + c8*81 for channel c8

      #pragma unroll
      for (int kd = 0; kd < 3; ++kd) {             // input slice = dd + kd
        const float* xrow = xci + (dd + kd)*(64*64);
        #pragma unroll
        for (int r = 0; r < 4; ++r) {              // patch row
          float2 lo = *reinterpret_cast<const float2*>(xrow + r*64);
          float2 hi = *reinterpret_cast<const float2*>(xrow + r*64 + 2);
          const float x0 = lo.x, x1 = lo.y, x2 = hi.x, x3 = hi.y;

          #pragma unroll
          for (int c8 = 0; c8 < 8; ++c8) {
            const float* wp = wci + c8*81;         // wave-uniform -> s_load
            #pragma unroll
            for (int dh = 0; dh < 2; ++dh) {
              const int kh = r - dh;
              if (kh < 0 || kh > 2) continue;
              const float w0 = wp[(kd*3 + kh)*3 + 0];
              const float w1 = wp[(kd*3 + kh)*3 + 1];
              const float w2 = wp[(kd*3 + kh)*3 + 2];
              acc[c8][dh*2 + 0] += w0*x0 + w1*x1 + w2*x2;
              acc[c8][dh*2 + 1] += w0*x1 + w1*x2 + w2*x3;
            }
          }
        }
      }
    }
    // fold this conv-d slice into the running per-channel window max
    #pragma unroll
    for (int c8 = 0; c8 < 8; ++c8) {
      float m = fmaxf(fmaxf(acc[c8][0], acc[c8][1]), fmaxf(acc[c8][2], acc[c8][3]));
      pm[c8] = fmaxf(pm[c8], m);
    }
  }

  float S = 0.f;
  #pragma unroll
  for (int c = 0; c < 8; ++c) S += pm[c];
  if (!valid) S = 0.f;

  // deterministic block reduction
  #pragma unroll
  for (int off = 32; off > 0; off >>= 1) S += __shfl_down(S, off, 64);
  if ((tid & 63) == 0) wsum[tid >> 6] = S;
  __syncthreads();
  if (tid == 0) {
    float tot = wsum[0] + wsum[1] + wsum[2] + wsum[3];
    ws[n*128 + (pd*8 + bx)] = tot;     // 120 slots per n, all written every launch
  }
}

__global__ void finalize_kernel(const float* __restrict__ ws,
                                const float* __restrict__ cb,
                                const float* __restrict__ bias,
                                float* __restrict__ out)
{
  int n = threadIdx.x;
  if (n >= 32) return;
  float tot = 0.f;
  #pragma unroll 1
  for (int s = 0; s < 120; ++s) tot += ws[n*128 + s];
  float C = 0.f;
  #pragma unroll 1
  for (int c = 0; c < 16; ++c) C += cb[c]*0.5f + bias[c];
  out[n] = tot * (1.0f/(2.0f*14415.0f)) + C;
}

extern "C" void kernel_launch(void* const* d_in, const int* in_sizes, int n_in,
                              void* d_out, int out_size, void* d_ws, size_t ws_size,
                              hipStream_t stream) {
  (void)in_sizes; (void)n_in; (void)out_size; (void)ws_size;
  const float* x    = (const float*)d_in[0];
  const float* wgt  = (const float*)d_in[1];
  const float* cb   = (const float*)d_in[2];
  const float* bias = (const float*)d_in[3];
  float* out = (float*)d_out;
  float* ws  = (float*)d_ws;     // needs 32*128*4 = 16 KB

  dim3 grid(8, 15, 32);          // (hw-tile x channel-group, pd, n) = 3840 blocks
  conv_pool_kernel<<<grid, 256, 0, stream>>>(x, wgt, ws);
  finalize_kernel<<<1, 64, 0, stream>>>(ws, cb, bias, out);
}

// Round 5
// 147.351 us; speedup vs baseline: 1.8631x; 1.8631x over previous
//
#include <hip/hip_runtime.h>

// Fused Conv3d(3->16,k3,valid) + bias + /2 + MaxPool3d(2) + GlobalAvgPool + bias + channel-sum
// N=32, Cin=3, D=32,H=64,W=64 -> conv (30,62,62) -> pool (15,31,31) -> out (32)
//
// out[n] = (1/(2*14415)) * sum_{c,windows} max_window(conv_c) + sum_c( conv_bias_c/2 + bias_c )
//
// Register-pressure-balanced: 4 channels per block (acc[4][8]=32 VGPR,
// 4*27=108 uniform weights), x patch (xr[16]) read straight from global and
// reused across both pool-d slices and all 4 channels. launch_bounds(256,2)
// (cap 128 VGPR) -- the (256,4) cap of 64 caused 200+ MB of scratch spill.

__global__ __launch_bounds__(256, 2) void conv_pool_kernel(
    const float* __restrict__ x, const float* __restrict__ wgt,
    float* __restrict__ ws)
{
  __shared__ float wsum[4];

  const int tid  = threadIdx.x;
  const int bx   = blockIdx.x;           // 0..15: tile = bx&3, channel-group g = bx>>2
  const int tile = bx & 3;
  const int g    = bx >> 2;              // channels g*4 .. g*4+3
  const int pht  = tile >> 1, pwt = tile & 1;
  const int pd   = blockIdx.y;           // 0..14
  const int n    = blockIdx.z;           // 0..31

  const int ty = tid >> 4, tx = tid & 15;
  const int ph = pht*16 + ty, pw = pwt*16 + tx;    // pooled coords, valid < 31
  const bool valid = (ph < 31) && (pw < 31);
  const int phc = (ph < 31) ? ph : 30;             // clamp: duplicate window, zeroed later
  const int pwc = (pw < 31) ? pw : 30;

  const float* xn = x + (size_t)n*(3*32*64*64) + (size_t)(2*pd)*(64*64);
  const int rowoff = (2*phc)*64 + 2*pwc;           // element offset within a d-slice

  float acc[4][8];
  #pragma unroll
  for (int c = 0; c < 4; ++c)
    #pragma unroll
    for (int i = 0; i < 8; ++i) acc[c][i] = 0.f;

  #pragma unroll 1
  for (int ci = 0; ci < 3; ++ci) {
    const float* xci = xn + (size_t)ci*(32*64*64);
    const float* wci = wgt + (size_t)(g*12 + ci)*27;   // ((g*4+c)*3+ci)*27 = this + c*81

    #pragma unroll
    for (int dq = 0; dq < 4; ++dq) {                   // input d-slice = 2*pd + dq
      // 4x4 (h,w) register patch, two 8B loads per row
      float xr[16];
      const float* xrow = xci + dq*(64*64) + rowoff;
      #pragma unroll
      for (int r = 0; r < 4; ++r) {
        float2 lo = *reinterpret_cast<const float2*>(xrow + r*64);
        float2 hi = *reinterpret_cast<const float2*>(xrow + r*64 + 2);
        xr[r*4+0] = lo.x; xr[r*4+1] = lo.y; xr[r*4+2] = hi.x; xr[r*4+3] = hi.y;
      }

      #pragma unroll
      for (int c = 0; c < 4; ++c) {
        const float* wp = wci + c*81;                  // wave-uniform -> s_load
        #pragma unroll
        for (int dd = 0; dd < 2; ++dd) {
          const int kd = dq - dd;
          if (kd < 0 || kd > 2) continue;
          #pragma unroll
          for (int r = 0; r < 4; ++r) {
            #pragma unroll
            for (int dh = 0; dh < 2; ++dh) {
              const int kh = r - dh;
              if (kh < 0 || kh > 2) continue;
              #pragma unroll
              for (int kw = 0; kw < 3; ++kw) {
                const float wv = wp[(kd*3 + kh)*3 + kw];
                acc[c][dd*4 + dh*2 + 0] += wv * xr[r*4 + kw + 0];
                acc[c][dd*4 + dh*2 + 1] += wv * xr[r*4 + kw + 1];
              }
            }
          }
        }
      }
    }
  }

  // maxpool each 2x2x2 window, sum over this block's 4 channels
  float S = 0.f;
  #pragma unroll
  for (int c = 0; c < 4; ++c) {
    float m = fmaxf(fmaxf(fmaxf(acc[c][0], acc[c][1]), fmaxf(acc[c][2], acc[c][3])),
                    fmaxf(fmaxf(acc[c][4], acc[c][5]), fmaxf(acc[c][6], acc[c][7])));
    S += m;
  }
  if (!valid) S = 0.f;

  // deterministic block reduction
  #pragma unroll
  for (int off = 32; off > 0; off >>= 1) S += __shfl_down(S, off, 64);
  if ((tid & 63) == 0) wsum[tid >> 6] = S;
  __syncthreads();
  if (tid == 0) {
    float tot = wsum[0] + wsum[1] + wsum[2] + wsum[3];
    ws[n*256 + (pd*16 + bx)] = tot;    // 240 slots per n, all written every launch
  }
}

__global__ void finalize_kernel(const float* __restrict__ ws,
                                const float* __restrict__ cb,
                                const float* __restrict__ bias,
                                float* __restrict__ out)
{
  int n = threadIdx.x;
  if (n >= 32) return;
  float tot = 0.f;
  #pragma unroll 1
  for (int s = 0; s < 240; ++s) tot += ws[n*256 + s];
  float C = 0.f;
  #pragma unroll 1
  for (int c = 0; c < 16; ++c) C += cb[c]*0.5f + bias[c];
  out[n] = tot * (1.0f/(2.0f*14415.0f)) + C;
}

extern "C" void kernel_launch(void* const* d_in, const int* in_sizes, int n_in,
                              void* d_out, int out_size, void* d_ws, size_t ws_size,
                              hipStream_t stream) {
  (void)in_sizes; (void)n_in; (void)out_size; (void)ws_size;
  const float* x    = (const float*)d_in[0];
  const float* wgt  = (const float*)d_in[1];
  const float* cb   = (const float*)d_in[2];
  const float* bias = (const float*)d_in[3];
  float* out = (float*)d_out;
  float* ws  = (float*)d_ws;     // needs 32*256*4 = 32 KB

  dim3 grid(16, 15, 32);         // (hw-tile x channel-group, pd, n) = 7680 blocks
  conv_pool_kernel<<<grid, 256, 0, stream>>>(x, wgt, ws);
  finalize_kernel<<<1, 64, 0, stream>>>(ws, cb, bias, out);
}

// Round 7
// 123.614 us; speedup vs baseline: 2.2209x; 1.1920x over previous
//
#include <hip/hip_runtime.h>

// Implicit-GEMM MFMA version.
// Conv3d(3->16,k3,valid)+bias, /2, MaxPool3d(2), GlobalAvgPool, +bias, channel-sum.
// out[n] = (1/(2*14415)) * sum_{c,windows} max_window(conv_c) + sum_c(cb_c/2 + bias_c)
//
// Block = (n, pd, ph): conv positions pos = d^*128 + h^*64 + w (w 0..61, pad 64),
// GEMM: A[pos][k] x B[k][ch], k = kd*32 + ci*9 + kh*3 + kw (27 used per 32-chunk).
// mfma_f32_16x16x32_bf16; C layout col=lane&15 (ch), row=(lane>>4)*4+reg (w).

using f32x4  = __attribute__((ext_vector_type(4))) float;
using bf16x8 = __attribute__((ext_vector_type(8))) short;
using u32x4  = __attribute__((ext_vector_type(4))) unsigned int;

__device__ inline unsigned short f2bf(float f) {
  unsigned int u = __float_as_uint(f);
  unsigned int r = 0x7fffu + ((u >> 16) & 1u);   // round-to-nearest-even (finite inputs)
  return (unsigned short)((u + r) >> 16);
}
__device__ inline unsigned int pack2(float a, float b) {
  return (unsigned int)f2bf(a) | ((unsigned int)f2bf(b) << 16);
}

__global__ __launch_bounds__(256, 2) void conv_mfma_kernel(
    const float* __restrict__ x, const float* __restrict__ wgt,
    float* __restrict__ ws)
{
  __shared__ __align__(16) float xs[3*4*4*64];            // 12 KB: [ci][4d][4h][64w]
  __shared__ __align__(16) unsigned int Abuf[256*4*4];    // 16 KB: 256 pos x 32 bf16 (1 kd-chunk)
  __shared__ __align__(16) unsigned int Wbuf[16*16*4];    // 4 KB: 16 ch x 96 bf16 (16 u4 slots)
  __shared__ float pool[4*32*16];                         // 8 KB: [wave(d^h^)][pw][ch]
  __shared__ float wsum[4];

  const int tid = threadIdx.x;
  const int ph  = blockIdx.x;       // 0..30
  const int pd  = blockIdx.y;       // 0..14
  const int n   = blockIdx.z;       // 0..31
  const int l   = tid & 63;
  const int wid = tid >> 6;

  // ---- stage x tile: [ci][2pd..2pd+3][2ph..2ph+3][0..63], 768 float4
  const float* xn = x + (size_t)n*(3*32*64*64);
  const int D0 = 2*pd, H0 = 2*ph;
  #pragma unroll
  for (int it = 0; it < 3; ++it) {
    int i = tid + it*256;                    // 0..767
    int row = i >> 4, c4 = i & 15;           // 48 rows x 16 float4
    int ci = row >> 4, rr = row & 15, d = rr >> 2, h = rr & 3;
    f32x4 v = *reinterpret_cast<const f32x4*>(
        xn + ((size_t)(ci*32 + D0 + d)*64 + (H0 + h))*64 + c4*4);
    *reinterpret_cast<f32x4*>(&xs[row*64 + c4*4]) = v;
  }

  // ---- stage weights: Wbuf[ch][chunk^swz] (8 bf16 per u4 slot), zero-padded k
  {
    int ch = tid >> 4, c16 = tid & 15;
    if (c16 < 12) {
      float wv[8];
      #pragma unroll
      for (int j = 0; j < 8; ++j) {
        int col = c16*8 + j;                 // 0..95
        int kdc = col >> 5, k27 = col & 31;
        float v = 0.f;
        if (k27 < 27) {
          int ci = k27 / 9, rem = k27 - 9*ci, kh = rem / 3, kw = rem - 3*kh;
          v = wgt[ch*81 + ci*27 + kdc*9 + kh*3 + kw];
        }
        wv[j] = v;
      }
      u32x4 q;
      q.x = pack2(wv[0], wv[1]); q.y = pack2(wv[2], wv[3]);
      q.z = pack2(wv[4], wv[5]); q.w = pack2(wv[6], wv[7]);
      *reinterpret_cast<u32x4*>(&Wbuf[(ch*16 + (c16 ^ (ch & 7)))*4]) = q;
    }
  }
  __syncthreads();

  // ---- position for this thread's A-row
  const int wpos = tid & 63;
  const int hh   = (tid >> 6) & 1;
  const int dd   = tid >> 7;
  const int wc   = (wpos < 62) ? wpos : 61;          // clamp pad cols (garbage -> pw31, dropped)
  const int xbase = dd*256 + hh*64 + wc;             // + ci*1024 + kd*256 + kh*64 + kw

  f32x4 acc[4];
  #pragma unroll
  for (int tq = 0; tq < 4; ++tq)
    #pragma unroll
    for (int q = 0; q < 4; ++q) acc[tq][q] = 0.f;

  const int ch = l & 15, lg = l >> 4;

  #pragma unroll
  for (int kdc = 0; kdc < 3; ++kdc) {
    // build A chunk: this thread's row = 32 bf16 (27 real + 5 zero)
    float val[32];
    #pragma unroll
    for (int ci = 0; ci < 3; ++ci)
      #pragma unroll
      for (int kh = 0; kh < 3; ++kh)
        #pragma unroll
        for (int kw = 0; kw < 3; ++kw)
          val[ci*9 + kh*3 + kw] = xs[xbase + ci*1024 + kdc*256 + kh*64 + kw];
    #pragma unroll
    for (int j = 27; j < 32; ++j) val[j] = 0.f;

    #pragma unroll
    for (int cc = 0; cc < 4; ++cc) {
      u32x4 q;
      q.x = pack2(val[cc*8+0], val[cc*8+1]);
      q.y = pack2(val[cc*8+2], val[cc*8+3]);
      q.z = pack2(val[cc*8+4], val[cc*8+5]);
      q.w = pack2(val[cc*8+6], val[cc*8+7]);
      *reinterpret_cast<u32x4*>(&Abuf[(tid*4 + (cc ^ (tid & 3)))*4]) = q;
    }
    __syncthreads();

    // MFMA: B-frag (ch = l&15, k = kdc*32 + lg*8 ..+8), A-frags for 4 w-tiles
    bf16x8 bfrag = *reinterpret_cast<const bf16x8*>(
        &Wbuf[(ch*16 + (((kdc*4) + lg) ^ (ch & 7)))*4]);
    #pragma unroll
    for (int tq = 0; tq < 4; ++tq) {
      int row = wid*64 + tq*16 + (l & 15);
      bf16x8 afrag = *reinterpret_cast<const bf16x8*>(
          &Abuf[(row*4 + (lg ^ (row & 3)))*4]);
      acc[tq] = __builtin_amdgcn_mfma_f32_16x16x32_bf16(afrag, bfrag, acc[tq], 0, 0, 0);
    }
    __syncthreads();
  }

  // ---- epilogue: in-lane w-pair max, pool[wave][pw][ch]
  #pragma unroll
  for (int tq = 0; tq < 4; ++tq) {
    float m0 = fmaxf(acc[tq][0], acc[tq][1]);
    float m1 = fmaxf(acc[tq][2], acc[tq][3]);
    int pw = tq*8 + lg*2;
    pool[(wid*32 + pw    )*16 + ch] = m0;
    pool[(wid*32 + pw + 1)*16 + ch] = m1;
  }
  __syncthreads();

  // ---- max over (d^,h^) waves, sum over (pw<=30, ch)
  float S = 0.f;
  #pragma unroll
  for (int rep = 0; rep < 2; ++rep) {
    int idx = tid + rep*256;
    if (idx < 31*16) {
      float v0 = pool[idx], v1 = pool[512 + idx];
      float v2 = pool[1024 + idx], v3 = pool[1536 + idx];
      S += fmaxf(fmaxf(v0, v1), fmaxf(v2, v3));
    }
  }
  #pragma unroll
  for (int off = 32; off > 0; off >>= 1) S += __shfl_down(S, off, 64);
  if ((tid & 63) == 0) wsum[tid >> 6] = S;
  __syncthreads();
  if (tid == 0)
    ws[n*512 + pd*31 + ph] = wsum[0] + wsum[1] + wsum[2] + wsum[3];
}

__global__ void finalize_kernel(const float* __restrict__ ws,
                                const float* __restrict__ cb,
                                const float* __restrict__ bias,
                                float* __restrict__ out)
{
  int n = threadIdx.x;
  if (n >= 32) return;
  float tot = 0.f;
  #pragma unroll 1
  for (int s = 0; s < 465; ++s) tot += ws[n*512 + s];
  float C = 0.f;
  #pragma unroll 1
  for (int c = 0; c < 16; ++c) C += cb[c]*0.5f + bias[c];
  out[n] = tot * (1.0f/(2.0f*14415.0f)) + C;
}

extern "C" void kernel_launch(void* const* d_in, const int* in_sizes, int n_in,
                              void* d_out, int out_size, void* d_ws, size_t ws_size,
                              hipStream_t stream) {
  (void)in_sizes; (void)n_in; (void)out_size; (void)ws_size;
  const float* x    = (const float*)d_in[0];
  const float* wgt  = (const float*)d_in[1];
  const float* cb   = (const float*)d_in[2];
  const float* bias = (const float*)d_in[3];
  float* out = (float*)d_out;
  float* ws  = (float*)d_ws;     // needs 32*512*4 = 64 KB

  dim3 grid(31, 15, 32);         // (ph, pd, n) = 14880 blocks
  conv_mfma_kernel<<<grid, 256, 0, stream>>>(x, wgt, ws);
  finalize_kernel<<<1, 64, 0, stream>>>(ws, cb, bias, out);
}

// Round 8
// 113.479 us; speedup vs baseline: 2.4192x; 1.0893x over previous
//
#include <hip/hip_runtime.h>

// Implicit-GEMM MFMA v2 — no im2col.
// Conv3d(3->16,k3,valid)+bias, /2, MaxPool3d(2), GlobalAvgPool, +bias, channel-sum.
// out[n] = (1/(2*14415)) * sum_{c,windows} max_window(conv_c) + sum_c(cb_c/2 + bias_c)
//
// Block = (n, pd, ph). LDS: xt[w][k], k=ci*16+d*4+h (48 real, pad 64), bf16,
// 16B-slot XOR-swizzle by (w&7). Wave wid=(dd,hh) builds its own B in regs:
// B[k][ch] = wgt[ch][ci][d-dd][h-hh][kw] (0 outside window); kw handled by 3
// accumulating MFMAs with A = xt rows shifted by kw. C: col=lane&15=ch,
// row=(lane>>4)*4+reg = w (m89 layout, verified R7).

using f32x4  = __attribute__((ext_vector_type(4))) float;
using bf16x8 = __attribute__((ext_vector_type(8))) short;
using s16x4  = __attribute__((ext_vector_type(4))) short;
using u32x4  = __attribute__((ext_vector_type(4))) unsigned int;

__device__ inline unsigned short f2bf(float f) {
  unsigned int u = __float_as_uint(f);
  unsigned int r = 0x7fffu + ((u >> 16) & 1u);   // RNE for finite inputs
  return (unsigned short)((u + r) >> 16);
}

__global__ __launch_bounds__(256, 4) void conv_mfma_kernel(
    const float* __restrict__ x, const float* __restrict__ wgt,
    float* __restrict__ ws)
{
  __shared__ __align__(16) unsigned short xt[68*64];   // 8704 B, swizzled
  __shared__ __align__(16) float wlds[1296];           // 5184 B
  __shared__ float pool[4*32*16];                      // 8192 B
  __shared__ float wsum[4];

  const int tid = threadIdx.x;
  const int ph  = blockIdx.x;       // 0..30
  const int pd  = blockIdx.y;       // 0..14
  const int n   = blockIdx.z;       // 0..31
  const int l   = tid & 63;
  const int wid = tid >> 6;
  const int ch  = l & 15, lg = l >> 4;
  const int hh  = wid & 1, dd = wid >> 1;

  // ---- zero xt (rows 64..67 + k>=48 pad stay zero; rest overwritten)
  {
    u32x4 z = {0, 0, 0, 0};
    #pragma unroll
    for (int it = 0; it < 3; ++it) {
      int i = tid + it*256;
      if (i < 544) *reinterpret_cast<u32x4*>(&xt[i*8]) = z;
    }
  }
  // ---- stage weights f32 -> LDS (coalesced)
  for (int i = tid; i < 1296; i += 256) wlds[i] = wgt[i];
  __syncthreads();

  // ---- stage x: xt[w][k] = bf16(x[ci][D0+d][H0+h][w]), k=ci*16+d*4+h
  const float* xn = x + (size_t)n*(3*32*64*64);
  const int D0 = 2*pd, H0 = 2*ph;
  {
    const int w = tid & 63, kq = tid >> 6;     // this thread: 12 k's for one w
    short va[12];
    #pragma unroll
    for (int t = 0; t < 12; ++t) {
      int k = kq*12 + t;
      int ci = k >> 4, d = (k >> 2) & 3, hq = k & 3;
      va[t] = (short)f2bf(xn[((size_t)(ci*32 + D0 + d)*64 + (H0 + hq))*64 + w]);
    }
    #pragma unroll
    for (int p = 0; p < 3; ++p) {
      int off = (kq*12 + p*4) ^ ((w & 7) << 3);   // u16 units; 16B-slot swizzle
      s16x4 v = { va[p*4], va[p*4+1], va[p*4+2], va[p*4+3] };
      *reinterpret_cast<s16x4*>(&xt[w*64 + off]) = v;
    }
  }

  // ---- build this wave's B fragments in registers (once per block)
  bf16x8 bfr[3][2];
  #pragma unroll
  for (int kw = 0; kw < 3; ++kw) {
    #pragma unroll
    for (int cchunk = 0; cchunk < 2; ++cchunk) {
      bf16x8 f;
      #pragma unroll
      for (int j = 0; j < 8; ++j) {
        int k = cchunk*32 + lg*8 + j;
        int ci = k >> 4, d = (k >> 2) & 3, hq = k & 3;
        int kd = d - dd, kh = hq - hh;
        bool ok = (ci < 3) && (kd >= 0) && (kd < 3) && (kh >= 0) && (kh < 3);
        int cic = ci < 3 ? ci : 2;
        int kdc = kd < 0 ? 0 : (kd > 2 ? 2 : kd);
        int khc = kh < 0 ? 0 : (kh > 2 ? 2 : kh);
        float v = wlds[ch*81 + cic*27 + kdc*9 + khc*3 + kw];
        f[j] = ok ? (short)f2bf(v) : (short)0;
      }
      bfr[kw][cchunk] = f;
    }
  }
  __syncthreads();

  // ---- main loop: 24 x (ds_read_b128 + mfma), no barriers
  f32x4 acc[4];
  #pragma unroll
  for (int tq = 0; tq < 4; ++tq)
    #pragma unroll
    for (int q = 0; q < 4; ++q) acc[tq][q] = 0.f;

  #pragma unroll
  for (int kw = 0; kw < 3; ++kw) {
    #pragma unroll
    for (int cchunk = 0; cchunk < 2; ++cchunk) {
      const int koff = cchunk*32 + lg*8;
      #pragma unroll
      for (int tq = 0; tq < 4; ++tq) {
        int row = tq*16 + (l & 15) + kw;        // A-tile rows shifted by kw
        bf16x8 af = *reinterpret_cast<const bf16x8*>(
            &xt[row*64 + (koff ^ ((row & 7) << 3))]);
        acc[tq] = __builtin_amdgcn_mfma_f32_16x16x32_bf16(af, bfr[kw][cchunk],
                                                          acc[tq], 0, 0, 0);
      }
    }
  }

  // ---- epilogue: in-lane w-pair max -> pool[wid][pw][ch]
  #pragma unroll
  for (int tq = 0; tq < 4; ++tq) {
    float m0 = fmaxf(acc[tq][0], acc[tq][1]);
    float m1 = fmaxf(acc[tq][2], acc[tq][3]);
    int pw = tq*8 + lg*2;
    pool[(wid*32 + pw    )*16 + ch] = m0;
    pool[(wid*32 + pw + 1)*16 + ch] = m1;
  }
  __syncthreads();

  // ---- max over the 4 (dd,hh) waves, sum over (pw<=30, ch)
  float S = 0.f;
  #pragma unroll
  for (int rep = 0; rep < 2; ++rep) {
    int idx = tid + rep*256;
    if (idx < 31*16) {
      float v0 = pool[idx], v1 = pool[512 + idx];
      float v2 = pool[1024 + idx], v3 = pool[1536 + idx];
      S += fmaxf(fmaxf(v0, v1), fmaxf(v2, v3));
    }
  }
  #pragma unroll
  for (int off = 32; off > 0; off >>= 1) S += __shfl_down(S, off, 64);
  if ((tid & 63) == 0) wsum[tid >> 6] = S;
  __syncthreads();
  if (tid == 0)
    ws[n*512 + pd*31 + ph] = wsum[0] + wsum[1] + wsum[2] + wsum[3];
}

__global__ void finalize_kernel(const float* __restrict__ ws,
                                const float* __restrict__ cb,
                                const float* __restrict__ bias,
                                float* __restrict__ out)
{
  int n = threadIdx.x;
  if (n >= 32) return;
  float tot = 0.f;
  #pragma unroll 1
  for (int s = 0; s < 465; ++s) tot += ws[n*512 + s];
  float C = 0.f;
  #pragma unroll 1
  for (int c = 0; c < 16; ++c) C += cb[c]*0.5f + bias[c];
  out[n] = tot * (1.0f/(2.0f*14415.0f)) + C;
}

extern "C" void kernel_launch(void* const* d_in, const int* in_sizes, int n_in,
                              void* d_out, int out_size, void* d_ws, size_t ws_size,
                              hipStream_t stream) {
  (void)in_sizes; (void)n_in; (void)out_size; (void)ws_size;
  const float* x    = (const float*)d_in[0];
  const float* wgt  = (const float*)d_in[1];
  const float* cb   = (const float*)d_in[2];
  const float* bias = (const float*)d_in[3];
  float* out = (float*)d_out;
  float* ws  = (float*)d_ws;     // needs 32*512*4 = 64 KB

  dim3 grid(31, 15, 32);         // (ph, pd, n) = 14880 blocks
  conv_mfma_kernel<<<grid, 256, 0, stream>>>(x, wgt, ws);
  finalize_kernel<<<1, 64, 0, stream>>>(ws, cb, bias, out);
}

// Round 9
// 87.613 us; speedup vs baseline: 3.1334x; 1.2952x over previous
//
#include <hip/hip_runtime.h>

// Implicit-GEMM MFMA v3 — block-invariant B-fragments hoisted to a prep kernel.
// Conv3d(3->16,k3,valid)+bias, /2, MaxPool3d(2), GlobalAvgPool, +bias, channel-sum.
// out[n] = (1/(2*14415)) * sum_{c,windows} max_window(conv_c) + sum_c(cb_c/2 + bias_c)
//
// Block = (n, pd, ph). LDS: xt[w][k], k=ci*16+d*4+h (48 real, pad 64), bf16,
// 16B-slot XOR-swizzle by (w&7). Wave wid=(dd,hh); B[k][ch] frags precomputed
// by prep_bfrags into ws (1536 x 16B, same for every block). kw handled by 3
// accumulating MFMAs with A = xt rows shifted by kw. C: col=lane&15=ch,
// row=(lane>>4)*4+reg = w.

using f32x4  = __attribute__((ext_vector_type(4))) float;
using bf16x8 = __attribute__((ext_vector_type(8))) short;
using s16x4  = __attribute__((ext_vector_type(4))) short;

__device__ inline unsigned short f2bf(float f) {
  unsigned int u = __float_as_uint(f);
  unsigned int r = 0x7fffu + ((u >> 16) & 1u);   // RNE for finite inputs
  return (unsigned short)((u + r) >> 16);
}

#define WS_FRAG_OFF 16384   // in floats: frags live at ws + 64 KB (needs ws >= 88 KB)

// ---- prep: B[k][ch] fragments for each (wid, kw, cchunk, lane). 1536 x 16B.
__global__ void prep_bfrags(const float* __restrict__ wgt, float* __restrict__ ws)
{
  const int tid = threadIdx.x;
  short* fb = (short*)((unsigned int*)ws + WS_FRAG_OFF);
  #pragma unroll
  for (int t = 0; t < 6; ++t) {
    int idx = tid + t*256;            // 0..1535
    int l = idx & 63, rest = idx >> 6;
    int cc = rest & 1, kw = (rest >> 1) % 3, wid = rest / 6;
    int ch = l & 15, lg = l >> 4;
    int hh = wid & 1, dd = wid >> 1;
    short f[8];
    #pragma unroll
    for (int j = 0; j < 8; ++j) {
      int k = cc*32 + lg*8 + j;
      int ci = k >> 4, d = (k >> 2) & 3, hq = k & 3;
      int kd = d - dd, kh = hq - hh;
      bool ok = (ci < 3) && (kd >= 0) && (kd < 3) && (kh >= 0) && (kh < 3);
      float v = ok ? wgt[ch*81 + ci*27 + kd*9 + kh*3 + kw] : 0.f;
      f[j] = (short)f2bf(v);
    }
    bf16x8 q = { f[0], f[1], f[2], f[3], f[4], f[5], f[6], f[7] };
    *reinterpret_cast<bf16x8*>(&fb[idx*8]) = q;
  }
}

__global__ __launch_bounds__(256, 4) void conv_mfma_kernel(
    const float* __restrict__ x, const float* __restrict__ ws_in,
    float* __restrict__ ws)
{
  __shared__ __align__(16) unsigned short xt[68*64];   // 8704 B, swizzled
  __shared__ float pool[4*32*16];                      // 8192 B
  __shared__ float wsum[4];

  const int tid = threadIdx.x;
  const int ph  = blockIdx.x;       // 0..30
  const int pd  = blockIdx.y;       // 0..14
  const int n   = blockIdx.z;       // 0..31
  const int l   = tid & 63;
  const int wid = tid >> 6;
  const int ch  = l & 15, lg = l >> 4;

  // ---- zero only the never-written pads: 4 missing 16B slots per row (k>=48
  // under the per-row XOR bijection) + rows 64..67 (A reads reach row 65).
  {
    const int w = tid & 63, p = tid >> 6;
    s16x4 z = {0, 0, 0, 0};
    *reinterpret_cast<s16x4*>(&xt[w*64 + ((48 + p*4) ^ ((w & 7) << 3))]) = z;
    if (tid < 64) *reinterpret_cast<s16x4*>(&xt[64*64 + tid*4]) = z;
  }

  // ---- stage x: xt[w][k] = bf16(x[ci][D0+d][H0+h][w]), k=ci*16+d*4+h (disjoint from pads)
  const float* xn = x + (size_t)n*(3*32*64*64);
  const int D0 = 2*pd, H0 = 2*ph;
  {
    const int w = tid & 63, kq = tid >> 6;     // this thread: 12 k's for one w
    short va[12];
    #pragma unroll
    for (int t = 0; t < 12; ++t) {
      int k = kq*12 + t;
      int ci = k >> 4, d = (k >> 2) & 3, hq = k & 3;
      va[t] = (short)f2bf(xn[((size_t)(ci*32 + D0 + d)*64 + (H0 + hq))*64 + w]);
    }
    #pragma unroll
    for (int p = 0; p < 3; ++p) {
      int off = (kq*12 + p*4) ^ ((w & 7) << 3);   // u16 units; 16B-slot swizzle
      s16x4 v = { va[p*4], va[p*4+1], va[p*4+2], va[p*4+3] };
      *reinterpret_cast<s16x4*>(&xt[w*64 + off]) = v;
    }
  }

  // ---- load this wave's 6 precomputed B fragments (coalesced, L2-hot)
  const short* fb = (const short*)((const unsigned int*)ws_in + WS_FRAG_OFF);
  bf16x8 bfr[3][2];
  #pragma unroll
  for (int kw = 0; kw < 3; ++kw)
    #pragma unroll
    for (int cc = 0; cc < 2; ++cc)
      bfr[kw][cc] = *reinterpret_cast<const bf16x8*>(
          &fb[(((wid*3 + kw)*2 + cc)*64 + l)*8]);
  __syncthreads();

  // ---- main loop: 24 x (ds_read_b128 + mfma), no barriers
  f32x4 acc[4];
  #pragma unroll
  for (int tq = 0; tq < 4; ++tq)
    #pragma unroll
    for (int q = 0; q < 4; ++q) acc[tq][q] = 0.f;

  #pragma unroll
  for (int kw = 0; kw < 3; ++kw) {
    #pragma unroll
    for (int cc = 0; cc < 2; ++cc) {
      const int koff = cc*32 + lg*8;
      #pragma unroll
      for (int tq = 0; tq < 4; ++tq) {
        int row = tq*16 + (l & 15) + kw;        // A-tile rows shifted by kw
        bf16x8 af = *reinterpret_cast<const bf16x8*>(
            &xt[row*64 + (koff ^ ((row & 7) << 3))]);
        acc[tq] = __builtin_amdgcn_mfma_f32_16x16x32_bf16(af, bfr[kw][cc],
                                                          acc[tq], 0, 0, 0);
      }
    }
  }

  // ---- epilogue: in-lane w-pair max -> pool[wid][pw][ch]
  #pragma unroll
  for (int tq = 0; tq < 4; ++tq) {
    float m0 = fmaxf(acc[tq][0], acc[tq][1]);
    float m1 = fmaxf(acc[tq][2], acc[tq][3]);
    int pw = tq*8 + lg*2;
    pool[(wid*32 + pw    )*16 + ch] = m0;
    pool[(wid*32 + pw + 1)*16 + ch] = m1;
  }
  __syncthreads();

  // ---- max over the 4 (dd,hh) waves, sum over (pw<=30, ch)
  float S = 0.f;
  #pragma unroll
  for (int rep = 0; rep < 2; ++rep) {
    int idx = tid + rep*256;
    if (idx < 31*16) {
      float v0 = pool[idx], v1 = pool[512 + idx];
      float v2 = pool[1024 + idx], v3 = pool[1536 + idx];
      S += fmaxf(fmaxf(v0, v1), fmaxf(v2, v3));
    }
  }
  #pragma unroll
  for (int off = 32; off > 0; off >>= 1) S += __shfl_down(S, off, 64);
  if ((tid & 63) == 0) wsum[tid >> 6] = S;
  __syncthreads();
  if (tid == 0)
    ws[n*512 + pd*31 + ph] = wsum[0] + wsum[1] + wsum[2] + wsum[3];
}

__global__ void finalize_kernel(const float* __restrict__ ws,
                                const float* __restrict__ cb,
                                const float* __restrict__ bias,
                                float* __restrict__ out)
{
  int n = threadIdx.x;
  if (n >= 32) return;
  float tot = 0.f;
  #pragma unroll 1
  for (int s = 0; s < 465; ++s) tot += ws[n*512 + s];
  float C = 0.f;
  #pragma unroll 1
  for (int c = 0; c < 16; ++c) C += cb[c]*0.5f + bias[c];
  out[n] = tot * (1.0f/(2.0f*14415.0f)) + C;
}

extern "C" void kernel_launch(void* const* d_in, const int* in_sizes, int n_in,
                              void* d_out, int out_size, void* d_ws, size_t ws_size,
                              hipStream_t stream) {
  (void)in_sizes; (void)n_in; (void)out_size; (void)ws_size;
  const float* x    = (const float*)d_in[0];
  const float* wgt  = (const float*)d_in[1];
  const float* cb   = (const float*)d_in[2];
  const float* bias = (const float*)d_in[3];
  float* out = (float*)d_out;
  float* ws  = (float*)d_ws;     // needs 64 KB partials + 24 KB frags = 88 KB

  prep_bfrags<<<1, 256, 0, stream>>>(wgt, ws);
  dim3 grid(31, 15, 32);         // (ph, pd, n) = 14880 blocks
  conv_mfma_kernel<<<grid, 256, 0, stream>>>(x, ws, ws);
  finalize_kernel<<<1, 64, 0, stream>>>(ws, cb, bias, out);
}

// Round 10
// 52.697 us; speedup vs baseline: 5.2096x; 1.6626x over previous
//
#include <hip/hip_runtime.h>

// Implicit-GEMM MFMA v4 — v3 + parallelized prep/finalize tail.
// Conv3d(3->16,k3,valid)+bias, /2, MaxPool3d(2), GlobalAvgPool, +bias, channel-sum.
// out[n] = (1/(2*14415)) * sum_{c,windows} max_window(conv_c) + sum_c(cb_c/2 + bias_c)
//
// Block = (n, pd, ph). LDS: xt[w][k], k=ci*16+d*4+h (48 real, pad 64), bf16,
// 16B-slot XOR-swizzle by (w&7). Wave wid=(dd,hh); B[k][ch] frags precomputed
// by prep_bfrags into ws (1536 x 16B, block-invariant). kw handled by 3
// accumulating MFMAs with A = xt rows shifted by kw. C: col=lane&15=ch,
// row=(lane>>4)*4+reg = w.

using f32x4  = __attribute__((ext_vector_type(4))) float;
using bf16x8 = __attribute__((ext_vector_type(8))) short;
using s16x4  = __attribute__((ext_vector_type(4))) short;

__device__ inline unsigned short f2bf(float f) {
  unsigned int u = __float_as_uint(f);
  unsigned int r = 0x7fffu + ((u >> 16) & 1u);   // RNE for finite inputs
  return (unsigned short)((u + r) >> 16);
}

#define WS_FRAG_OFF 16384   // in floats: frags live at ws + 64 KB (needs ws >= 88 KB)

// ---- prep: B[k][ch] fragments for each (wid, kw, cchunk, lane). 1536 x 16B.
__global__ void prep_bfrags(const float* __restrict__ wgt, float* __restrict__ ws)
{
  short* fb = (short*)((unsigned int*)ws + WS_FRAG_OFF);
  int idx = blockIdx.x*256 + threadIdx.x;   // 0..1535
  int l = idx & 63, rest = idx >> 6;
  int cc = rest & 1, kw = (rest >> 1) % 3, wid = rest / 6;
  int ch = l & 15, lg = l >> 4;
  int hh = wid & 1, dd = wid >> 1;
  short f[8];
  #pragma unroll
  for (int j = 0; j < 8; ++j) {
    int k = cc*32 + lg*8 + j;
    int ci = k >> 4, d = (k >> 2) & 3, hq = k & 3;
    int kd = d - dd, kh = hq - hh;
    bool ok = (ci < 3) && (kd >= 0) && (kd < 3) && (kh >= 0) && (kh < 3);
    float v = ok ? wgt[ch*81 + ci*27 + kd*9 + kh*3 + kw] : 0.f;
    f[j] = (short)f2bf(v);
  }
  bf16x8 q = { f[0], f[1], f[2], f[3], f[4], f[5], f[6], f[7] };
  *reinterpret_cast<bf16x8*>(&fb[idx*8]) = q;
}

__global__ __launch_bounds__(256, 4) void conv_mfma_kernel(
    const float* __restrict__ x, const float* __restrict__ ws_in,
    float* __restrict__ ws)
{
  __shared__ __align__(16) unsigned short xt[68*64];   // 8704 B, swizzled
  __shared__ float pool[4*32*16];                      // 8192 B
  __shared__ float wsum[4];

  const int tid = threadIdx.x;
  const int ph  = blockIdx.x;       // 0..30
  const int pd  = blockIdx.y;       // 0..14
  const int n   = blockIdx.z;       // 0..31
  const int l   = tid & 63;
  const int wid = tid >> 6;
  const int ch  = l & 15, lg = l >> 4;

  // ---- zero only the never-written pads: 4 missing 16B slots per row (k>=48
  // under the per-row XOR bijection) + rows 64..67 (A reads reach row 65).
  {
    const int w = tid & 63, p = tid >> 6;
    s16x4 z = {0, 0, 0, 0};
    *reinterpret_cast<s16x4*>(&xt[w*64 + ((48 + p*4) ^ ((w & 7) << 3))]) = z;
    if (tid < 64) *reinterpret_cast<s16x4*>(&xt[64*64 + tid*4]) = z;
  }

  // ---- stage x: xt[w][k] = bf16(x[ci][D0+d][H0+h][w]), k=ci*16+d*4+h (disjoint from pads)
  const float* xn = x + (size_t)n*(3*32*64*64);
  const int D0 = 2*pd, H0 = 2*ph;
  {
    const int w = tid & 63, kq = tid >> 6;     // this thread: 12 k's for one w
    short va[12];
    #pragma unroll
    for (int t = 0; t < 12; ++t) {
      int k = kq*12 + t;
      int ci = k >> 4, d = (k >> 2) & 3, hq = k & 3;
      va[t] = (short)f2bf(xn[((size_t)(ci*32 + D0 + d)*64 + (H0 + hq))*64 + w]);
    }
    #pragma unroll
    for (int p = 0; p < 3; ++p) {
      int off = (kq*12 + p*4) ^ ((w & 7) << 3);   // u16 units; 16B-slot swizzle
      s16x4 v = { va[p*4], va[p*4+1], va[p*4+2], va[p*4+3] };
      *reinterpret_cast<s16x4*>(&xt[w*64 + off]) = v;
    }
  }

  // ---- load this wave's 6 precomputed B fragments (coalesced, L2-hot)
  const short* fb = (const short*)((const unsigned int*)ws_in + WS_FRAG_OFF);
  bf16x8 bfr[3][2];
  #pragma unroll
  for (int kw = 0; kw < 3; ++kw)
    #pragma unroll
    for (int cc = 0; cc < 2; ++cc)
      bfr[kw][cc] = *reinterpret_cast<const bf16x8*>(
          &fb[(((wid*3 + kw)*2 + cc)*64 + l)*8]);
  __syncthreads();

  // ---- main loop: 24 x (ds_read_b128 + mfma), no barriers
  f32x4 acc[4];
  #pragma unroll
  for (int tq = 0; tq < 4; ++tq)
    #pragma unroll
    for (int q = 0; q < 4; ++q) acc[tq][q] = 0.f;

  #pragma unroll
  for (int kw = 0; kw < 3; ++kw) {
    #pragma unroll
    for (int cc = 0; cc < 2; ++cc) {
      const int koff = cc*32 + lg*8;
      #pragma unroll
      for (int tq = 0; tq < 4; ++tq) {
        int row = tq*16 + (l & 15) + kw;        // A-tile rows shifted by kw
        bf16x8 af = *reinterpret_cast<const bf16x8*>(
            &xt[row*64 + (koff ^ ((row & 7) << 3))]);
        acc[tq] = __builtin_amdgcn_mfma_f32_16x16x32_bf16(af, bfr[kw][cc],
                                                          acc[tq], 0, 0, 0);
      }
    }
  }

  // ---- epilogue: in-lane w-pair max -> pool[wid][pw][ch]
  #pragma unroll
  for (int tq = 0; tq < 4; ++tq) {
    float m0 = fmaxf(acc[tq][0], acc[tq][1]);
    float m1 = fmaxf(acc[tq][2], acc[tq][3]);
    int pw = tq*8 + lg*2;
    pool[(wid*32 + pw    )*16 + ch] = m0;
    pool[(wid*32 + pw + 1)*16 + ch] = m1;
  }
  __syncthreads();

  // ---- max over the 4 (dd,hh) waves, sum over (pw<=30, ch)
  float S = 0.f;
  #pragma unroll
  for (int rep = 0; rep < 2; ++rep) {
    int idx = tid + rep*256;
    if (idx < 31*16) {
      float v0 = pool[idx], v1 = pool[512 + idx];
      float v2 = pool[1024 + idx], v3 = pool[1536 + idx];
      S += fmaxf(fmaxf(v0, v1), fmaxf(v2, v3));
    }
  }
  #pragma unroll
  for (int off = 32; off > 0; off >>= 1) S += __shfl_down(S, off, 64);
  if ((tid & 63) == 0) wsum[tid >> 6] = S;
  __syncthreads();
  if (tid == 0)
    ws[n*512 + pd*31 + ph] = wsum[0] + wsum[1] + wsum[2] + wsum[3];
}

// ---- finalize: one block per n, 64 lanes stride the 465 partials.
__global__ void finalize_kernel(const float* __restrict__ ws,
                                const float* __restrict__ cb,
                                const float* __restrict__ bias,
                                float* __restrict__ out)
{
  const int n = blockIdx.x, l = threadIdx.x;
  float t = 0.f;
  #pragma unroll
  for (int r = 0; r < 8; ++r) {
    int s = l + r*64;
    if (s < 465) t += ws[n*512 + s];
  }
  #pragma unroll
  for (int off = 32; off > 0; off >>= 1) t += __shfl_down(t, off, 64);
  if (l == 0) {
    float C = 0.f;
    #pragma unroll
    for (int c = 0; c < 16; ++c) C += cb[c]*0.5f + bias[c];
    out[n] = t * (1.0f/(2.0f*14415.0f)) + C;
  }
}

extern "C" void kernel_launch(void* const* d_in, const int* in_sizes, int n_in,
                              void* d_out, int out_size, void* d_ws, size_t ws_size,
                              hipStream_t stream) {
  (void)in_sizes; (void)n_in; (void)out_size; (void)ws_size;
  const float* x    = (const float*)d_in[0];
  const float* wgt  = (const float*)d_in[1];
  const float* cb   = (const float*)d_in[2];
  const float* bias = (const float*)d_in[3];
  float* out = (float*)d_out;
  float* ws  = (float*)d_ws;     // needs 64 KB partials + 24 KB frags = 88 KB

  prep_bfrags<<<6, 256, 0, stream>>>(wgt, ws);
  dim3 grid(31, 15, 32);         // (ph, pd, n) = 14880 blocks
  conv_mfma_kernel<<<grid, 256, 0, stream>>>(x, ws, ws);
  finalize_kernel<<<32, 64, 0, stream>>>(ws, cb, bias, out);
}

// Round 11
// 51.590 us; speedup vs baseline: 5.3214x; 1.0215x over previous
//
#include <hip/hip_runtime.h>

// Implicit-GEMM MFMA v5 — 3 pool-d slices per block (amortize staging/epilogue).
// Conv3d(3->16,k3,valid)+bias, /2, MaxPool3d(2), GlobalAvgPool, +bias, channel-sum.
// out[n] = (1/(2*14415)) * sum_{c,windows} max_window(conv_c) + sum_c(cb_c/2 + bias_c)
//
// Block = (ph, pdg, n), pdg covers pd = 3*pdg..3*pdg+2. Per-pd LDS xt[p][w][k],
// k=ci*16+drel*4+h (48 real, pad 64), bf16, 16B-slot XOR swizzle by (w&7).
// Wave wid=(dd,hh); B[k][ch] frags precomputed (block-invariant, in ws).
// kw via 3 accumulating MFMAs, A = xt rows shifted by kw. C: col=lane&15=ch,
// row=(lane>>4)*4+reg = w. Single pool[3] + ONE barrier pair per block.

using f32x4  = __attribute__((ext_vector_type(4))) float;
using bf16x8 = __attribute__((ext_vector_type(8))) short;
using s16x4  = __attribute__((ext_vector_type(4))) short;

__device__ inline unsigned short f2bf(float f) {
  unsigned int u = __float_as_uint(f);
  unsigned int r = 0x7fffu + ((u >> 16) & 1u);   // RNE for finite inputs
  return (unsigned short)((u + r) >> 16);
}

#define WS_FRAG_OFF 16384   // u32 units: frags at ws + 64 KB (needs ws >= 88 KB)

// ---- prep: B[k][ch] fragments for each (wid, kw, cchunk, lane). 1536 x 16B.
__global__ void prep_bfrags(const float* __restrict__ wgt, float* __restrict__ ws)
{
  short* fb = (short*)((unsigned int*)ws + WS_FRAG_OFF);
  int idx = blockIdx.x*256 + threadIdx.x;   // 0..1535
  int l = idx & 63, rest = idx >> 6;
  int cc = rest & 1, kw = (rest >> 1) % 3, wid = rest / 6;
  int ch = l & 15, lg = l >> 4;
  int hh = wid & 1, dd = wid >> 1;
  short f[8];
  #pragma unroll
  for (int j = 0; j < 8; ++j) {
    int k = cc*32 + lg*8 + j;
    int ci = k >> 4, d = (k >> 2) & 3, hq = k & 3;
    int kd = d - dd, kh = hq - hh;
    bool ok = (ci < 3) && (kd >= 0) && (kd < 3) && (kh >= 0) && (kh < 3);
    float v = ok ? wgt[ch*81 + ci*27 + kd*9 + kh*3 + kw] : 0.f;
    f[j] = (short)f2bf(v);
  }
  bf16x8 q = { f[0], f[1], f[2], f[3], f[4], f[5], f[6], f[7] };
  *reinterpret_cast<bf16x8*>(&fb[idx*8]) = q;
}

__global__ __launch_bounds__(256, 3) void conv_mfma_kernel(
    const float* __restrict__ x, const float* __restrict__ ws_in,
    float* __restrict__ ws)
{
  __shared__ __align__(16) unsigned short xt[3][66*64];  // 25,344 B, swizzled
  __shared__ float pool[3*4*32*16];                      // 24,576 B: [p][wid][pw][ch]
  __shared__ float wsum[4];

  const int tid = threadIdx.x;
  const int ph  = blockIdx.x;       // 0..30
  const int pdg = blockIdx.y;       // 0..4  -> pd = 3*pdg + p
  const int n   = blockIdx.z;       // 0..31
  const int l   = tid & 63;
  const int wid = tid >> 6;
  const int ch  = l & 15, lg = l >> 4;

  const int w  = tid & 63;
  const int kq = tid >> 6;

  // ---- zero never-written pads: k-slots 48..63 rows 0..63 (per buffer, thread
  // (w,kq) owns one s16x4 per buffer under the XOR bijection) + rows 64..65.
  {
    s16x4 z = {0, 0, 0, 0};
    #pragma unroll
    for (int b = 0; b < 3; ++b)
      *reinterpret_cast<s16x4*>(&xt[b][w*64 + ((48 + kq*4) ^ ((w & 7) << 3))]) = z;
    if (tid < 32) {
      #pragma unroll
      for (int b = 0; b < 3; ++b)
        *reinterpret_cast<s16x4*>(&xt[b][64*64 + tid*4]) = z;
    }
  }

  // ---- stage x: 8 unique d-slices (abs d = 6*pdg + s), write to each pd buffer
  // p with drel = s-2p in [0,4). k = ci*16 + drel*4 + h, swizzled 16B slots.
  const float* xn = x + (size_t)n*(3*32*64*64);
  const int D0b = 6*pdg, H0 = 2*ph;
  #pragma unroll
  for (int j = 0; j < 6; ++j) {
    int q = kq + 4*j;                  // 0..23, wave-uniform parts (ci,s)
    int ci = q >> 3, s = q & 7;
    const float* xp = xn + ((size_t)(ci*32 + D0b + s)*64 + H0)*64 + w;
    short va[4];
    #pragma unroll
    for (int h = 0; h < 4; ++h) va[h] = (short)f2bf(xp[h*64]);
    s16x4 v = { va[0], va[1], va[2], va[3] };
    #pragma unroll
    for (int p = 0; p < 3; ++p) {
      int drel = s - 2*p;
      if (drel >= 0 && drel < 4) {
        int off = (ci*16 + drel*4) ^ ((w & 7) << 3);
        *reinterpret_cast<s16x4*>(&xt[p][w*64 + off]) = v;
      }
    }
  }

  // ---- load this wave's 6 precomputed B fragments (coalesced, L2-hot)
  const short* fb = (const short*)((const unsigned int*)ws_in + WS_FRAG_OFF);
  bf16x8 bfr[3][2];
  #pragma unroll
  for (int kw = 0; kw < 3; ++kw)
    #pragma unroll
    for (int cc = 0; cc < 2; ++cc)
      bfr[kw][cc] = *reinterpret_cast<const bf16x8*>(
          &fb[(((wid*3 + kw)*2 + cc)*64 + l)*8]);
  __syncthreads();

  // ---- 3 pds: each 24 x (ds_read_b128 + mfma), epilogue to pool[p]
  #pragma unroll 1
  for (int p = 0; p < 3; ++p) {
    f32x4 acc[4];
    #pragma unroll
    for (int tq = 0; tq < 4; ++tq)
      #pragma unroll
      for (int qq = 0; qq < 4; ++qq) acc[tq][qq] = 0.f;

    #pragma unroll
    for (int kw = 0; kw < 3; ++kw) {
      #pragma unroll
      for (int cc = 0; cc < 2; ++cc) {
        const int koff = cc*32 + lg*8;
        #pragma unroll
        for (int tq = 0; tq < 4; ++tq) {
          int row = tq*16 + (l & 15) + kw;
          bf16x8 af = *reinterpret_cast<const bf16x8*>(
              &xt[p][row*64 + (koff ^ ((row & 7) << 3))]);
          acc[tq] = __builtin_amdgcn_mfma_f32_16x16x32_bf16(af, bfr[kw][cc],
                                                            acc[tq], 0, 0, 0);
        }
      }
    }
    // in-lane w-pair max -> pool[p][wid][pw][ch]
    #pragma unroll
    for (int tq = 0; tq < 4; ++tq) {
      float m0 = fmaxf(acc[tq][0], acc[tq][1]);
      float m1 = fmaxf(acc[tq][2], acc[tq][3]);
      int pw = tq*8 + lg*2;
      pool[(p*2048) + wid*512 + (pw    )*16 + ch] = m0;
      pool[(p*2048) + wid*512 + (pw + 1)*16 + ch] = m1;
    }
  }
  __syncthreads();

  // ---- max over 4 wids, sum over (p, pw<=30, ch)
  float S = 0.f;
  #pragma unroll
  for (int r = 0; r < 6; ++r) {
    int idx = tid + r*256;             // 0..1535 = [p][pw*16+ch]
    int p = idx >> 9, q = idx & 511;
    if (q < 496) {                     // pw < 31
      float v0 = pool[p*2048 +    0 + q], v1 = pool[p*2048 +  512 + q];
      float v2 = pool[p*2048 + 1024 + q], v3 = pool[p*2048 + 1536 + q];
      S += fmaxf(fmaxf(v0, v1), fmaxf(v2, v3));
    }
  }
  #pragma unroll
  for (int off = 32; off > 0; off >>= 1) S += __shfl_down(S, off, 64);
  if ((tid & 63) == 0) wsum[tid >> 6] = S;
  __syncthreads();
  if (tid == 0)
    ws[n*512 + pdg*31 + ph] = wsum[0] + wsum[1] + wsum[2] + wsum[3];
}

// ---- finalize: one block per n, 64 lanes stride the 155 partials.
__global__ void finalize_kernel(const float* __restrict__ ws,
                                const float* __restrict__ cb,
                                const float* __restrict__ bias,
                                float* __restrict__ out)
{
  const int n = blockIdx.x, l = threadIdx.x;
  float t = 0.f;
  #pragma unroll
  for (int r = 0; r < 3; ++r) {
    int s = l + r*64;
    if (s < 155) t += ws[n*512 + s];
  }
  #pragma unroll
  for (int off = 32; off > 0; off >>= 1) t += __shfl_down(t, off, 64);
  if (l == 0) {
    float C = 0.f;
    #pragma unroll
    for (int c = 0; c < 16; ++c) C += cb[c]*0.5f + bias[c];
    out[n] = t * (1.0f/(2.0f*14415.0f)) + C;
  }
}

extern "C" void kernel_launch(void* const* d_in, const int* in_sizes, int n_in,
                              void* d_out, int out_size, void* d_ws, size_t ws_size,
                              hipStream_t stream) {
  (void)in_sizes; (void)n_in; (void)out_size; (void)ws_size;
  const float* x    = (const float*)d_in[0];
  const float* wgt  = (const float*)d_in[1];
  const float* cb   = (const float*)d_in[2];
  const float* bias = (const float*)d_in[3];
  float* out = (float*)d_out;
  float* ws  = (float*)d_ws;     // 64 KB partials + 24 KB frags = 88 KB

  prep_bfrags<<<6, 256, 0, stream>>>(wgt, ws);
  dim3 grid(31, 5, 32);          // (ph, pdg, n) = 4960 blocks
  conv_mfma_kernel<<<grid, 256, 0, stream>>>(x, ws, ws);
  finalize_kernel<<<32, 64, 0, stream>>>(ws, cb, bias, out);
}